// Round 4
// baseline (1037.529 us; speedup 1.0000x reference)
//
#include <hip/hip_runtime.h>

#define FS 11
#define HFS 5

constexpr int Bn = 8, Cn = 19, Hn = 512, Wn = 512;
constexpr int HWn = Hn * Wn;            // 262144
constexpr int CHWn = Cn * HWn;          // 4980736
constexpr int TOTn = Bn * CHWn;         // 39845888

// tile: 16 rows x 64 cols -> 2048 blocks = 8 blocks/CU (32 waves/CU)
constexpr int TH = 16, TW = 64;
constexpr int HR  = TH + 10;            // 26 halo rows (h0-5 .. h0+20)
constexpr int HC4 = 20;                 // 80 halo cols = 20 float4 (w0-8 .. w0+71)
constexpr int NP4 = HR * HC4;           // 520 halo float4 items
constexpr int QS  = 84;                 // qs stride; 84%32=20 -> r-minor reads conflict-free
constexpr int WSS = 68;                 // ws stride; 68%32=4
constexpr int NTASK = HR * 8;           // 208 convW tasks (one per thread)

// wave-uniform float -> SGPR
__device__ __forceinline__ float rfl(float x) {
    return __uint_as_float(__builtin_amdgcn_readfirstlane(__float_as_uint(x)));
}

// taps[b][dim][j]: dim0 = kh (H-direction), dim1 = kw (W-direction, scaled by weight)
__global__ void k_taps(const float* __restrict__ spacing,
                       const float* __restrict__ inv_theta,
                       const float* __restrict__ wgt,
                       float* __restrict__ taps) {
    int t = threadIdx.x;
    if (t < Bn * 2 * FS) {
        int j = t % FS;
        int dim = (t / FS) & 1;
        int b = t / (2 * FS);
        float d = spacing[b * 2 + dim] * (float)(j - HFS);
        float a = d * inv_theta[dim];
        float k = __expf(-0.5f * a * a);
        if (j == HFS) k = 0.0f;          // message passing excludes self
        if (dim == 1) k *= wgt[0];       // fold smoothness_weight into kw
        taps[t] = k;
    }
}

// One block = one (b, 16x64 tile), all 19 channels.
// iteration c: stage qs=exp(px)*rinv | BAR | prefetch px(c+1),x0(c) issue |
//              convW (r-minor tasks, conflict-free) -> ws | BAR | convH + x0-add.
__global__ __launch_bounds__(256, 6) void k_fused(const float* __restrict__ xin,
                                                  const float* __restrict__ x0,
                                                  float* __restrict__ xout,
                                                  const float* __restrict__ taps) {
    __shared__ float qs[HR * QS];        // 8736 B
    __shared__ float ws[HR * WSS];       // 7072 B   (15808 B total)

    const int tid = threadIdx.x;
    // XCD-chunked swizzle: 2048 blocks = 8 XCDs x 256 tiles (one image per XCD)
    const int id = blockIdx.x;
    const int fl = (id & 7) * 256 + (id >> 3);
    const int b  = fl >> 8;              // image
    const int t8 = fl & 255;
    const int h0 = (t8 >> 3) * TH;       // 32 tile-rows
    const int w0 = (t8 & 7) * TW;        // 8 tile-cols

    const float* tp = taps + b * (2 * FS);
    float kh[FS], kw[FS];
#pragma unroll
    for (int j = 0; j < FS; j++) { kh[j] = rfl(tp[j]); kw[j] = rfl(tp[FS + j]); }

    const float* xb = xin + b * CHWn;

    // ---- per-thread halo items (same mapping for pass1 and stage) ----
    int off[3], lo[3];
    bool it[3], act[3];
#pragma unroll
    for (int k = 0; k < 3; k++) {
        int i = tid + 256 * k;
        it[k] = (i < NP4);
        int r = i / HC4, c4 = i % HC4;
        int hh = h0 - 5 + r;
        int ww = w0 - 8 + 4 * c4;
        act[k] = it[k] && hh >= 0 && hh < Hn && ww >= 0 && ww <= Wn - 4;
        off[k] = hh * Wn + ww;
        lo[k]  = r * QS + 4 * c4;
    }

    // ---- pass 1: rinv = 1/sum_c exp(x_c) in registers; keep c=0 raw x as px ----
    float4 px[3], rinv[3];
    {
        float4 s[3];
#pragma unroll
        for (int k = 0; k < 3; k++) {
            s[k] = make_float4(0.f, 0.f, 0.f, 0.f);
            if (act[k]) {
                float4 v = *(const float4*)(xb + off[k]);
                px[k] = v;
                s[k].x = __expf(v.x); s[k].y = __expf(v.y);
                s[k].z = __expf(v.z); s[k].w = __expf(v.w);
            }
        }
#pragma unroll 2
        for (int c = 1; c < Cn; ++c) {
#pragma unroll
            for (int k = 0; k < 3; k++) {
                if (!act[k]) continue;
                float4 v = *(const float4*)(xb + c * HWn + off[k]);
                s[k].x += __expf(v.x); s[k].y += __expf(v.y);
                s[k].z += __expf(v.z); s[k].w += __expf(v.w);
            }
        }
#pragma unroll
        for (int k = 0; k < 3; k++)
            if (act[k])
                rinv[k] = make_float4(1.f / s[k].x, 1.f / s[k].y,
                                      1.f / s[k].z, 1.f / s[k].w);
    }

    // ---- convW task geometry: r-minor so 8 consecutive lanes hit distinct banks ----
    const bool wact = tid < NTASK;
    const int wr = tid % HR;             // row 0..25 (minor)
    const int wg = tid / HR;             // col group 0..7
    const int qrd = wr * QS  + 8 * wg;   // qs read base (cols 8g..8g+23)
    const int wwr = wr * WSS + 8 * wg;   // ws write base

    // ---- convH geometry: 1 row x 4 cols per thread ----
    const int rs  = tid >> 4;            // out row 0..15
    const int cg  = tid & 15;            // col quad
    const int bws = rs * WSS + 4 * cg;
    const int pix = (h0 + rs) * Wn + (w0 + 4 * cg);

#pragma unroll 1
    for (int c = 0; c < Cn; ++c) {
        // stage: qs = exp(x_c) * rinv (zeros outside image = zero-pad semantics)
#pragma unroll
        for (int k = 0; k < 3; k++) {
            if (!it[k]) continue;
            float4 qv = make_float4(0.f, 0.f, 0.f, 0.f);
            if (act[k]) {
                qv.x = __expf(px[k].x) * rinv[k].x;
                qv.y = __expf(px[k].y) * rinv[k].y;
                qv.z = __expf(px[k].z) * rinv[k].z;
                qv.w = __expf(px[k].w) * rinv[k].w;
            }
            *(float4*)&qs[lo[k]] = qv;
        }
        __syncthreads();

        // prefetch: next channel's x (consumed by next stage) + this channel's x0
        if (c + 1 < Cn) {
#pragma unroll
            for (int k = 0; k < 3; k++)
                if (act[k]) px[k] = *(const float4*)(xb + (c + 1) * HWn + off[k]);
        }
        const int gi = (b * Cn + c) * HWn + pix;
        const float4 xA = *(const float4*)(x0 + gi);

        // convW: one task per thread (208 active)
        if (wact) {
            float t[24];
#pragma unroll
            for (int m = 0; m < 6; ++m)
                *(float4*)&t[4 * m] = *(const float4*)&qs[qrd + 4 * m];
            float o[8];
#pragma unroll
            for (int k2 = 0; k2 < 8; ++k2) {
                float a = 0.f;
#pragma unroll
                for (int j = 0; j < FS; ++j) {
                    if (j == HFS) continue;          // center tap zero
                    a = fmaf(kw[j], t[k2 + 3 + j], a);
                }
                o[k2] = a;
            }
            float4 oa = {o[0], o[1], o[2], o[3]};
            float4 ob = {o[4], o[5], o[6], o[7]};
            *(float4*)&ws[wwr]     = oa;
            *(float4*)&ws[wwr + 4] = ob;
        }
        __syncthreads();

        // convH + epilogue: read 10 ws rows (skip center), add x0, store
        {
            float4 o = {0.f, 0.f, 0.f, 0.f};
#pragma unroll
            for (int j = 0; j < FS; ++j) {
                if (j == HFS) continue;
                float4 v = *(const float4*)&ws[bws + j * WSS];
                float kj = kh[j];
                o.x = fmaf(kj, v.x, o.x); o.y = fmaf(kj, v.y, o.y);
                o.z = fmaf(kj, v.z, o.z); o.w = fmaf(kj, v.w, o.w);
            }
            float4 ra = {xA.x + o.x, xA.y + o.y, xA.z + o.z, xA.w + o.w};
            *(float4*)(xout + gi) = ra;
        }
        // no 3rd barrier: next stage writes qs (convW reads done at 2nd BAR);
        // next convW's ws writes are ordered by the next stage's barrier.
    }
}

extern "C" void kernel_launch(void* const* d_in, const int* in_sizes, int n_in,
                              void* d_out, int out_size, void* d_ws, size_t ws_size,
                              hipStream_t stream) {
    const float* x0      = (const float*)d_in[0];
    const float* spacing = (const float*)d_in[1];
    const float* wgt     = (const float*)d_in[2];
    const float* itheta  = (const float*)d_in[3];
    float* out = (float*)d_out;

    float* A    = (float*)d_ws;          // ping-pong buffer (TOTn floats)
    float* taps = A + TOTn;

    k_taps<<<1, 256, 0, stream>>>(spacing, itheta, wgt, taps);

    // 2048 blocks, 1D; XCD swizzle + tile decode in-kernel (8 x 32 x 8 tiles)
    // double-buffered iterations: no kernel reads and writes the same tensor
    k_fused<<<2048, 256, 0, stream>>>(x0,  x0, out, taps);   // it0
    k_fused<<<2048, 256, 0, stream>>>(out, x0, A,   taps);   // it1
    k_fused<<<2048, 256, 0, stream>>>(A,   x0, out, taps);   // it2
    k_fused<<<2048, 256, 0, stream>>>(out, x0, A,   taps);   // it3
    k_fused<<<2048, 256, 0, stream>>>(A,   x0, out, taps);   // it4
}

// Round 5
// 837.253 us; speedup vs baseline: 1.2392x; 1.2392x over previous
//
#include <hip/hip_runtime.h>

#define FS 11
#define HFS 5

constexpr int Bn = 8, Cn = 19, Hn = 512, Wn = 512;
constexpr int HWn = Hn * Wn;            // 262144
constexpr int CHWn = Cn * HWn;          // 4980736
constexpr int TOTn = Bn * CHWn;         // 39845888

// fused tile params (round-2 best-known geometry)
constexpr int TH = 32, TW = 64;
constexpr int HR  = TH + 10;            // 42 halo rows (h0-5 .. h0+36)
constexpr int HC4 = 20;                 // 80 halo cols = 20 float4 (w0-8 .. w0+71)
constexpr int NP4 = HR * HC4;           // 840 float4 halo pixels
constexpr int QS  = 84;                 // qs row stride
constexpr int WSS = 68;                 // ws row stride

// LDS-only barrier: orders ds_read/ds_write across the block but leaves global
// loads (vmcnt) in flight. All cross-thread hazards in this kernel are LDS.
__device__ __forceinline__ void lds_barrier() {
    asm volatile("s_waitcnt lgkmcnt(0)" ::: "memory");
    __builtin_amdgcn_s_barrier();
}

// wave-uniform float -> SGPR
__device__ __forceinline__ float rfl(float x) {
    return __uint_as_float(__builtin_amdgcn_readfirstlane(__float_as_uint(x)));
}

// taps[b][dim][j]: dim0 = kh (H-direction), dim1 = kw (W-direction, scaled by weight)
__global__ void k_taps(const float* __restrict__ spacing,
                       const float* __restrict__ inv_theta,
                       const float* __restrict__ wgt,
                       float* __restrict__ taps) {
    int t = threadIdx.x;
    if (t < Bn * 2 * FS) {
        int j = t % FS;
        int dim = (t / FS) & 1;
        int b = t / (2 * FS);
        float d = spacing[b * 2 + dim] * (float)(j - HFS);
        float a = d * inv_theta[dim];
        float k = __expf(-0.5f * a * a);
        if (j == HFS) k = 0.0f;          // message passing excludes self
        if (dim == 1) k *= wgt[0];       // fold smoothness_weight into kw
        taps[t] = k;
    }
}

// One block = one (b, 32x64 tile), all 19 channels.
// iteration c: stage qs=exp(px)*rinv | LDSBAR | issue px(c+1)+x0(c) loads |
//              convW -> ws | LDSBAR | convH + x0-add.
// Raw (lgkmcnt-only) barriers keep the global prefetches in flight across the
// whole channel iteration; they are waited on only at the next stage's use.
__global__ __launch_bounds__(256, 4) void k_fused(const float* __restrict__ xin,
                                                  const float* __restrict__ x0,
                                                  float* __restrict__ xout,
                                                  const float* __restrict__ taps) {
    __shared__ float qs[HR * QS];        // 14112 B
    __shared__ float ws[HR * WSS];       // 11424 B  (total 25536 B)

    const int tid = threadIdx.x;
    // XCD-chunked swizzle: 1024 blocks = 8 XCDs x 128 tiles (one image per XCD)
    const int id = blockIdx.x;
    const int fl = (id & 7) * 128 + (id >> 3);
    const int b  = fl >> 7;
    const int t7 = fl & 127;
    const int h0 = (t7 >> 3) * TH;       // 16 tile-rows
    const int w0 = (t7 & 7) * TW;        // 8 tile-cols

    const float* tp = taps + b * (2 * FS);
    float kh[FS], kw[FS];
#pragma unroll
    for (int j = 0; j < FS; j++) { kh[j] = rfl(tp[j]); kw[j] = rfl(tp[FS + j]); }

    const float* xb = xin + b * CHWn;

    // ---- per-thread halo items (same mapping reused by pass1 and every stage) ----
    int off[4], lo[4];
    bool act[4], it[4];
#pragma unroll
    for (int k = 0; k < 4; k++) {
        int i = tid + 256 * k;
        it[k] = (i < NP4);
        int r = i / HC4, c4 = i % HC4;
        int hh = h0 - 5 + r;
        int ww = w0 - 8 + 4 * c4;
        act[k] = it[k] && hh >= 0 && hh < Hn && ww >= 0 && ww <= Wn - 4;
        off[k] = hh * Wn + ww;
        lo[k]  = r * QS + 4 * c4;
    }

    // ---- pass 1: rinv = 1/sum_c exp(x_c) per halo pixel, in registers;
    //      channel 0's raw x retained in px (free prefetch for stage 0) ----
    float4 px[4], rinv[4];
    {
        float4 s[4];
#pragma unroll
        for (int k = 0; k < 4; k++) {
            s[k] = make_float4(0.f, 0.f, 0.f, 0.f);
            if (act[k]) {
                float4 v = *(const float4*)(xb + off[k]);
                px[k] = v;
                s[k].x = __expf(v.x); s[k].y = __expf(v.y);
                s[k].z = __expf(v.z); s[k].w = __expf(v.w);
            }
        }
#pragma unroll 2
        for (int c = 1; c < Cn; ++c) {
#pragma unroll
            for (int k = 0; k < 4; k++) {
                if (!act[k]) continue;
                float4 v = *(const float4*)(xb + c * HWn + off[k]);
                s[k].x += __expf(v.x); s[k].y += __expf(v.y);
                s[k].z += __expf(v.z); s[k].w += __expf(v.w);
            }
        }
#pragma unroll
        for (int k = 0; k < 4; k++)
            if (act[k])
                rinv[k] = make_float4(1.f / s[k].x, 1.f / s[k].y,
                                      1.f / s[k].z, 1.f / s[k].w);
    }

    const int t0  = 2 * (tid >> 4);      // phase-B output rows t0, t0+1
    const int col = 4 * (tid & 15);      // phase-B output cols col..col+3
    const int pix = (h0 + t0) * Wn + (w0 + col);

    // ---- channel loop ----
    for (int c = 0; c < Cn; ++c) {
        // stage: qs = exp(x_c) * rinv (zeros outside image = zero-pad semantics)
        // (compiler inserts the vmcnt wait for px here — one full channel after issue)
#pragma unroll
        for (int k = 0; k < 4; k++) {
            if (!it[k]) continue;
            float4 qv = make_float4(0.f, 0.f, 0.f, 0.f);
            if (act[k]) {
                qv.x = __expf(px[k].x) * rinv[k].x;
                qv.y = __expf(px[k].y) * rinv[k].y;
                qv.z = __expf(px[k].z) * rinv[k].z;
                qv.w = __expf(px[k].w) * rinv[k].w;
            }
            *(float4*)&qs[lo[k]] = qv;
        }
        lds_barrier();

        // issue prefetches: next channel's x (for next stage) + this channel's x0;
        // these stay in flight across both raw barriers below
        if (c + 1 < Cn) {
#pragma unroll
            for (int k = 0; k < 4; k++)
                if (act[k]) px[k] = *(const float4*)(xb + (c + 1) * HWn + off[k]);
        }
        const int gi = (b * Cn + c) * HWn + pix;
        float4 xA = *(const float4*)(x0 + gi);
        float4 xB = *(const float4*)(x0 + gi + Wn);

        // phase A: convW for all 42 halo rows; task = (row r, 8-col group g)
#pragma unroll 1
        for (int i2 = tid; i2 < HR * 8; i2 += 256) {
            int r = i2 >> 3, g = i2 & 7;
            float t[24];
#pragma unroll
            for (int m = 0; m < 6; ++m)
                *(float4*)&t[4 * m] = *(const float4*)&qs[r * QS + 8 * g + 4 * m];
            float o[8];
#pragma unroll
            for (int k2 = 0; k2 < 8; ++k2) {
                float a = 0.f;
#pragma unroll
                for (int j = 0; j < FS; ++j) {
                    if (j == HFS) continue;     // center tap zero
                    a = fmaf(kw[j], t[k2 + 3 + j], a);
                }
                o[k2] = a;
            }
            float4 oa = {o[0], o[1], o[2], o[3]};
            float4 ob = {o[4], o[5], o[6], o[7]};
            *(float4*)&ws[r * WSS + 8 * g]     = oa;
            *(float4*)&ws[r * WSS + 8 * g + 4] = ob;
        }
        lds_barrier();

        // phase B: convH (2 rows x 4 cols per thread) + x0-add, coalesced f4 stores
        {
            float4 wv[12];
#pragma unroll
            for (int j = 0; j < 12; ++j)
                wv[j] = *(const float4*)&ws[(t0 + j) * WSS + col];
            float4 o0 = {0.f, 0.f, 0.f, 0.f}, o1 = {0.f, 0.f, 0.f, 0.f};
#pragma unroll
            for (int j = 0; j < FS; ++j) {
                if (j == HFS) continue;
                float kj = kh[j];
                o0.x = fmaf(kj, wv[j].x, o0.x);     o0.y = fmaf(kj, wv[j].y, o0.y);
                o0.z = fmaf(kj, wv[j].z, o0.z);     o0.w = fmaf(kj, wv[j].w, o0.w);
                o1.x = fmaf(kj, wv[j + 1].x, o1.x); o1.y = fmaf(kj, wv[j + 1].y, o1.y);
                o1.z = fmaf(kj, wv[j + 1].z, o1.z); o1.w = fmaf(kj, wv[j + 1].w, o1.w);
            }
            float4 ra = {xA.x + o0.x, xA.y + o0.y, xA.z + o0.z, xA.w + o0.w};
            float4 rb = {xB.x + o1.x, xB.y + o1.y, xB.z + o1.z, xB.w + o1.w};
            *(float4*)(xout + gi)      = ra;
            *(float4*)(xout + gi + Wn) = rb;
        }
        // no 3rd barrier needed: phase-B ds_reads are drained by each thread's
        // lgkmcnt(0) at the NEXT stage's barrier, before any thread can start
        // the next convW's ws writes.
    }
}

extern "C" void kernel_launch(void* const* d_in, const int* in_sizes, int n_in,
                              void* d_out, int out_size, void* d_ws, size_t ws_size,
                              hipStream_t stream) {
    const float* x0      = (const float*)d_in[0];
    const float* spacing = (const float*)d_in[1];
    const float* wgt     = (const float*)d_in[2];
    const float* itheta  = (const float*)d_in[3];
    float* out = (float*)d_out;

    float* A    = (float*)d_ws;          // ping-pong buffer (TOTn floats)
    float* taps = A + TOTn;

    k_taps<<<1, 256, 0, stream>>>(spacing, itheta, wgt, taps);

    // 1024 blocks, 1D; XCD swizzle + tile decode in-kernel (8 images x 16 x 8 tiles)
    // double-buffered iterations: no kernel reads and writes the same tensor
    k_fused<<<1024, 256, 0, stream>>>(x0,  x0, out, taps);   // it0
    k_fused<<<1024, 256, 0, stream>>>(out, x0, A,   taps);   // it1
    k_fused<<<1024, 256, 0, stream>>>(A,   x0, out, taps);   // it2
    k_fused<<<1024, 256, 0, stream>>>(out, x0, A,   taps);   // it3
    k_fused<<<1024, 256, 0, stream>>>(A,   x0, out, taps);   // it4
}